// Round 1
// baseline (570.563 us; speedup 1.0000x reference)
//
#include <hip/hip_runtime.h>
#include <hip/hip_bf16.h>

typedef __attribute__((ext_vector_type(8))) short bfrag_t;
typedef __attribute__((ext_vector_type(4))) float facc_t;

#define B_ 4
#define S_ 4096
#define D_ 256

__device__ __forceinline__ short f2bf(float f) {
  union { float fv; unsigned u; } x; x.fv = f;
  unsigned r = x.u + 0x7FFFu + ((x.u >> 16) & 1u);
  return (short)(r >> 16);
}

__device__ __forceinline__ facc_t mfma16(bfrag_t a, bfrag_t b, facc_t c) {
  return __builtin_amdgcn_mfma_f32_16x16x32_bf16(a, b, c, 0, 0, 0);
}

// ---- transpose weights to bf16: WT[p][e][d] = W_p[d][e] --------------------
__global__ void wt_kernel(const float* __restrict__ Wq, const float* __restrict__ Wk,
                          const float* __restrict__ Wv, short* __restrict__ WT) {
  const float* W = (blockIdx.x == 0) ? Wq : ((blockIdx.x == 1) ? Wk : Wv);
  short* o = WT + blockIdx.x * (D_ * D_);
  int t = threadIdx.x;
  #pragma unroll 4
  for (int i = 0; i < D_; ++i) {
    o[t * D_ + i] = f2bf(W[i * D_ + t]);   // coalesced read, scattered 2B write (tiny)
  }
}

// ---- QKV projection: X[16384,256] fp32 -> Qb (scaled 1/16), Kb, VT bf16 ----
__global__ __launch_bounds__(256) void proj_kernel(
    const float* __restrict__ X, const short* __restrict__ WT,
    short* __restrict__ Qb, short* __restrict__ Kb, short* __restrict__ VT) {
  const int tid  = threadIdx.x;
  const int wave = tid >> 6, lane = tid & 63;
  const int lrow = lane & 15, kch = lane >> 4;
  const int row0 = blockIdx.x * 64 + wave * 16;   // 16 rows per wave
  const int arow = row0 + lrow;
  const int bblk = row0 >> 12;                    // batch index (64 | 4096)

  // A-frags: X rows in bf16, k = kt*32 + kch*8 + e  (contiguous 8)
  bfrag_t af[8];
  #pragma unroll
  for (int kt = 0; kt < 8; ++kt) {
    const float* src = X + (size_t)arow * D_ + kt * 32 + kch * 8;
    float4 a = *reinterpret_cast<const float4*>(src);
    float4 b = *reinterpret_cast<const float4*>(src + 4);
    bfrag_t f;
    f[0] = f2bf(a.x); f[1] = f2bf(a.y); f[2] = f2bf(a.z); f[3] = f2bf(a.w);
    f[4] = f2bf(b.x); f[5] = f2bf(b.y); f[6] = f2bf(b.z); f[7] = f2bf(b.w);
    af[kt] = f;
  }

  #pragma unroll 1
  for (int p = 0; p < 3; ++p) {
    const short* Wp = WT + p * (D_ * D_);
    facc_t acc[16];
    #pragma unroll
    for (int nt = 0; nt < 16; ++nt) acc[nt] = (facc_t)0.0f;
    #pragma unroll
    for (int kt = 0; kt < 8; ++kt) {
      #pragma unroll
      for (int nt = 0; nt < 16; ++nt) {
        // B[k][n] = W[k][n] = WT[n][k]: contiguous 8 along k
        bfrag_t bf = *reinterpret_cast<const bfrag_t*>(
            Wp + (nt * 16 + lrow) * D_ + kt * 32 + kch * 8);
        acc[nt] = mfma16(af[kt], bf, acc[nt]);
      }
    }
    // C/D layout: row = kch*4 + r (local), col = nt*16 + lrow
    if (p == 0) {
      #pragma unroll
      for (int nt = 0; nt < 16; ++nt)
        #pragma unroll
        for (int r = 0; r < 4; ++r)
          Qb[(size_t)(row0 + kch * 4 + r) * D_ + nt * 16 + lrow] =
              f2bf(acc[nt][r] * 0.0625f);   // fold 1/sqrt(256)
    } else if (p == 1) {
      #pragma unroll
      for (int nt = 0; nt < 16; ++nt)
        #pragma unroll
        for (int r = 0; r < 4; ++r)
          Kb[(size_t)(row0 + kch * 4 + r) * D_ + nt * 16 + lrow] = f2bf(acc[nt][r]);
    } else {
      #pragma unroll
      for (int nt = 0; nt < 16; ++nt)
        #pragma unroll
        for (int r = 0; r < 4; ++r) {
          int srow = row0 + kch * 4 + r;
          int d = nt * 16 + lrow;
          VT[((size_t)(bblk * D_ + d)) * S_ + (srow & (S_ - 1))] = f2bf(acc[nt][r]);
        }
    }
  }
}

// ---- flash attention: Qb (pre-scaled), Kb row-major, VT transposed ---------
__global__ __launch_bounds__(256) void attn_kernel(
    const short* __restrict__ Qb, const short* __restrict__ Kb,
    const short* __restrict__ VT, float* __restrict__ Out) {
  __shared__ __align__(16) short Pl[4][16][72];   // per-wave P buffer, 16B-aligned rows
  const int tid  = threadIdx.x;
  const int wave = tid >> 6, lane = tid & 63;
  const int lrow = lane & 15, kch = lane >> 4;
  const int b  = blockIdx.x >> 6;
  const int qt = blockIdx.x & 63;
  const int q0 = qt * 64 + wave * 16;             // wave's q-row base (within batch)

  // hoist Q A-frags
  bfrag_t qf[8];
  #pragma unroll
  for (int kt = 0; kt < 8; ++kt)
    qf[kt] = *reinterpret_cast<const bfrag_t*>(
        Qb + ((size_t)b * S_ + q0 + lrow) * D_ + kt * 32 + kch * 8);

  facc_t oacc[16];
  #pragma unroll
  for (int nt = 0; nt < 16; ++nt) oacc[nt] = (facc_t)0.0f;
  float mrow[4], lsum[4];
  #pragma unroll
  for (int r = 0; r < 4; ++r) { mrow[r] = -3.0e38f; lsum[r] = 0.0f; }

  const short* Kbp = Kb + (size_t)b * S_ * D_;
  const short* Vbp = VT + (size_t)b * D_ * S_;

  #pragma unroll 1
  for (int t = 0; t < S_ / 64; ++t) {
    const int kv0 = t * 64;
    // ---- scores S = Q K^T (pre-scaled via Q) ----
    facc_t sacc[4];
    #pragma unroll
    for (int nt = 0; nt < 4; ++nt) sacc[nt] = (facc_t)0.0f;
    #pragma unroll
    for (int kt = 0; kt < 8; ++kt) {
      #pragma unroll
      for (int nt = 0; nt < 4; ++nt) {
        bfrag_t kf = *reinterpret_cast<const bfrag_t*>(
            Kbp + (size_t)(kv0 + nt * 16 + lrow) * D_ + kt * 32 + kch * 8);
        sacc[nt] = mfma16(qf[kt], kf, sacc[nt]);
      }
    }
    // ---- online softmax (rows live in reg r, cols across 16-lane group) ----
    float pv[4][4];
    float sf[4];
    #pragma unroll
    for (int r = 0; r < 4; ++r) {
      float mx = fmaxf(fmaxf(sacc[0][r], sacc[1][r]), fmaxf(sacc[2][r], sacc[3][r]));
      mx = fmaxf(mx, __shfl_xor(mx, 1));
      mx = fmaxf(mx, __shfl_xor(mx, 2));
      mx = fmaxf(mx, __shfl_xor(mx, 4));
      mx = fmaxf(mx, __shfl_xor(mx, 8));
      float mn = fmaxf(mrow[r], mx);
      sf[r] = __expf(mrow[r] - mn);
      mrow[r] = mn;
      float s = 0.0f;
      #pragma unroll
      for (int nt = 0; nt < 4; ++nt) {
        float e = __expf(sacc[nt][r] - mn);
        pv[nt][r] = e;
        s += e;
      }
      s += __shfl_xor(s, 1); s += __shfl_xor(s, 2);
      s += __shfl_xor(s, 4); s += __shfl_xor(s, 8);
      lsum[r] = lsum[r] * sf[r] + s;
    }
    facc_t sfv;
    sfv[0] = sf[0]; sfv[1] = sf[1]; sfv[2] = sf[2]; sfv[3] = sf[3];
    #pragma unroll
    for (int nt = 0; nt < 16; ++nt) oacc[nt] *= sfv;
    // ---- P -> LDS (C-layout write), read back as A-frags ----
    #pragma unroll
    for (int nt = 0; nt < 4; ++nt)
      #pragma unroll
      for (int r = 0; r < 4; ++r)
        Pl[wave][kch * 4 + r][nt * 16 + lrow] = f2bf(pv[nt][r]);
    asm volatile("s_waitcnt lgkmcnt(0)" ::: "memory");
    bfrag_t pf0 = *reinterpret_cast<const bfrag_t*>(&Pl[wave][lrow][kch * 8]);
    bfrag_t pf1 = *reinterpret_cast<const bfrag_t*>(&Pl[wave][lrow][32 + kch * 8]);
    // ---- O += P V  (B-frags contiguous from VT) ----
    #pragma unroll
    for (int nt = 0; nt < 16; ++nt) {
      const short* vrow = Vbp + (size_t)(nt * 16 + lrow) * S_ + kv0 + kch * 8;
      bfrag_t vf0 = *reinterpret_cast<const bfrag_t*>(vrow);
      oacc[nt] = mfma16(pf0, vf0, oacc[nt]);
      bfrag_t vf1 = *reinterpret_cast<const bfrag_t*>(vrow + 32);
      oacc[nt] = mfma16(pf1, vf1, oacc[nt]);
    }
  }
  // ---- epilogue: normalize and store fp32 ----
  float inv[4];
  #pragma unroll
  for (int r = 0; r < 4; ++r) inv[r] = 1.0f / lsum[r];
  #pragma unroll
  for (int nt = 0; nt < 16; ++nt)
    #pragma unroll
    for (int r = 0; r < 4; ++r)
      Out[((size_t)b * S_ + q0 + kch * 4 + r) * D_ + nt * 16 + lrow] =
          oacc[nt][r] * inv[r];
}

extern "C" void kernel_launch(void* const* d_in, const int* in_sizes, int n_in,
                              void* d_out, int out_size, void* d_ws, size_t ws_size,
                              hipStream_t stream) {
  const float* X  = (const float*)d_in[0];
  const float* Wq = (const float*)d_in[1];
  const float* Wk = (const float*)d_in[2];
  const float* Wv = (const float*)d_in[3];
  float* out = (float*)d_out;

  char* ws = (char*)d_ws;
  short* Qb = (short*)(ws);                       // 16384*256 bf16 = 8 MB
  short* Kb = (short*)(ws + 8388608);             // 8 MB
  short* VT = (short*)(ws + 16777216);            // 8 MB (V transposed [B][D][S])
  short* WT = (short*)(ws + 25165824);            // 3*256*256 bf16 = 384 KB

  wt_kernel<<<3, 256, 0, stream>>>(Wq, Wk, Wv, WT);
  proj_kernel<<<256, 256, 0, stream>>>(X, WT, Qb, Kb, VT);
  attn_kernel<<<256, 256, 0, stream>>>(Qb, Kb, VT, out);
}